// Round 5
// baseline (300.187 us; speedup 1.0000x reference)
//
#include <hip/hip_runtime.h>
#include <hip/hip_fp16.h>
#include <math.h>

#define TPB 256
#define CTPB 512
#define KTPB 512

// ---------- complex helpers ----------
__device__ __forceinline__ float2 cmul(float2 a, float2 b) {
    return make_float2(a.x * b.x - a.y * b.y, a.x * b.y + a.y * b.x);
}
__device__ __forceinline__ float2 cmulcj(float2 a, float2 b) {  // a * conj(b)
    return make_float2(a.x * b.x + a.y * b.y, a.y * b.x - a.x * b.y);
}
__device__ __forceinline__ float2 cdivf(float2 a, float2 b) {
    float inv = 1.0f / (b.x * b.x + b.y * b.y);
    return make_float2((a.x * b.x + a.y * b.y) * inv, (a.y * b.x - a.x * b.y) * inv);
}
__device__ __forceinline__ float2 cadd(float2 a, float2 b) { return make_float2(a.x + b.x, a.y + b.y); }
__device__ __forceinline__ float2 csub(float2 a, float2 b) { return make_float2(a.x - b.x, a.y - b.y); }
__device__ __forceinline__ float2 mul_i(float2 a, float d) {  // a * (i*d)
    return make_float2(-d * a.y, d * a.x);
}
__device__ __forceinline__ int brev11(int x) { return (int)(__brev((unsigned)x) >> 21); }
// base-8 digit reversal of a 12-bit index (4 digits)
__device__ __forceinline__ int rev8(int x) {
    return ((x & 7) << 9) | (((x >> 3) & 7) << 6) | (((x >> 6) & 7) << 3) | ((x >> 9) & 7);
}
// LDS bank swizzle. GF(2)-LINEAR: swz(a^b) == swz(a)^swz(b) -> per-tap offsets fold
// to compile-time XOR constants.
__device__ __forceinline__ int swz(int i) { return i ^ ((i >> 4) & 15) ^ ((i >> 8) & 15); }

// ---------- 8-point DFT cores ----------
__device__ __forceinline__ void dft8(const float2* x, float2* y, float d) {
    const float r = 0.70710678118f;
    float2 s0 = cadd(x[0], x[4]), t0 = csub(x[0], x[4]);
    float2 s1 = cadd(x[1], x[5]), t1 = csub(x[1], x[5]);
    float2 s2 = cadd(x[2], x[6]), t2 = csub(x[2], x[6]);
    float2 s3 = cadd(x[3], x[7]), t3 = csub(x[3], x[7]);
    t1 = cmul(t1, make_float2(r, d * r));
    t2 = mul_i(t2, d);
    t3 = cmul(t3, make_float2(-r, d * r));
    float2 u0 = cadd(s0, s2), v0 = csub(s0, s2);
    float2 u1 = cadd(s1, s3), v1 = mul_i(csub(s1, s3), d);
    y[0] = cadd(u0, u1); y[4] = csub(u0, u1);
    y[2] = cadd(v0, v1); y[6] = csub(v0, v1);
    float2 p0 = cadd(t0, t2), q0 = csub(t0, t2);
    float2 p1 = cadd(t1, t3), q1 = mul_i(csub(t1, t3), d);
    y[1] = cadd(p0, p1); y[5] = csub(p0, p1);
    y[3] = cadd(q0, q1); y[7] = csub(q0, q1);
}

// dft8 with x[4..7] == 0 (zero-padded upper half): level 1 vanishes
__device__ __forceinline__ void dft8z(float2 x0, float2 x1, float2 x2, float2 x3,
                                      float2* y, float d) {
    const float r = 0.70710678118f;
    float2 u0 = cadd(x0, x2), v0 = csub(x0, x2);
    float2 u1 = cadd(x1, x3), v1 = mul_i(csub(x1, x3), d);
    float2 t1 = cmul(x1, make_float2(r, d * r));
    float2 t2 = mul_i(x2, d);
    float2 t3 = cmul(x3, make_float2(-r, d * r));
    float2 p0 = cadd(x0, t2), q0 = csub(x0, t2);
    float2 p1 = cadd(t1, t3), q1 = mul_i(csub(t1, t3), d);
    y[0] = cadd(u0, u1); y[4] = csub(u0, u1);
    y[2] = cadd(v0, v1); y[6] = csub(v0, v1);
    y[1] = cadd(p0, p1); y[5] = csub(p0, p1);
    y[3] = cadd(q0, q1); y[7] = csub(q0, q1);
}

// dft8 computing only outputs y[0..3] — for the discarded tail
__device__ __forceinline__ void dft8_lo(const float2* x, float2* y, float d) {
    const float r = 0.70710678118f;
    float2 s0 = cadd(x[0], x[4]), t0 = csub(x[0], x[4]);
    float2 s1 = cadd(x[1], x[5]), t1 = csub(x[1], x[5]);
    float2 s2 = cadd(x[2], x[6]), t2 = csub(x[2], x[6]);
    float2 s3 = cadd(x[3], x[7]), t3 = csub(x[3], x[7]);
    t1 = cmul(t1, make_float2(r, d * r));
    t2 = mul_i(t2, d);
    t3 = cmul(t3, make_float2(-r, d * r));
    float2 u0 = cadd(s0, s2), v0 = csub(s0, s2);
    float2 u1 = cadd(s1, s3), v1 = mul_i(csub(s1, s3), d);
    y[0] = cadd(u0, u1);
    y[2] = cadd(v0, v1);
    float2 p0 = cadd(t0, t2), q0 = csub(t0, t2);
    float2 p1 = cadd(t1, t3), q1 = mul_i(csub(t1, t3), d);
    y[1] = cadd(p0, p1);
    y[3] = cadd(q0, q1);
}

// ---------- single radix-8 stages for conv (1 butterfly/thread, N=4096, NT=512) ----------
template <int HB, int DIR>
__device__ __forceinline__ void dif_stage(float2* s, int tid) {
    __syncthreads();
    const int h = 1 << HB;
    int j = tid & (h - 1);
    int base = ((tid >> HB) << (HB + 3)) + j;
    int s0 = swz(base);
    float2 x[8];
#pragma unroll
    for (int k = 0; k < 8; ++k) x[k] = s[s0 ^ swz(k << HB)];
    float2 y[8];
    dft8(x, y, (float)DIR);
    if constexpr (HB != 0) {
        float ang = (float)DIR * 6.283185307179586f / (float)(h << 3) * (float)j;
        float c, sn;
        __sincosf(ang, &sn, &c);
        float2 w = make_float2(c, sn), wm = w;
        s[s0] = y[0];
#pragma unroll
        for (int m = 1; m < 8; ++m) {
            s[s0 ^ swz(m << HB)] = cmul(wm, y[m]);
            wm = cmul(wm, w);
        }
    } else {
#pragma unroll
        for (int m = 0; m < 8; ++m) s[s0 ^ swz(m << HB)] = y[m];
    }
}

template <int HB, int DIR>
__device__ __forceinline__ void dit_stage(float2* s, int tid) {
    __syncthreads();
    const int h = 1 << HB;
    int j = tid & (h - 1);
    int base = ((tid >> HB) << (HB + 3)) + j;
    int s0 = swz(base);
    float2 x[8];
    if constexpr (HB != 0) {
        float ang = (float)DIR * 6.283185307179586f / (float)(h << 3) * (float)j;
        float c, sn;
        __sincosf(ang, &sn, &c);
        float2 w = make_float2(c, sn);
        x[0] = s[s0];
        float2 wm = w;
#pragma unroll
        for (int k = 1; k < 8; ++k) {
            x[k] = cmul(wm, s[s0 ^ swz(k << HB)]);
            wm = cmul(wm, w);
        }
    } else {
#pragma unroll
        for (int k = 0; k < 8; ++k) x[k] = s[s0 ^ swz(k << HB)];
    }
    float2 y[8];
    dft8(x, y, (float)DIR);
#pragma unroll
    for (int m = 0; m < 8; ++m) s[s0 ^ swz(m << HB)] = y[m];
}

// ---------- generic radix-8 DIF (for kprep), with h=1 twiddle skip ----------
template <int LOGN, int NT>
__device__ void fft8_dif(float2* s, int tid, float dir) {
    const int N = 1 << LOGN;
#pragma unroll
    for (int hb = LOGN - 3; hb >= 0; hb -= 3) {
        const int h = 1 << hb;
        const float astep = dir * 6.283185307179586f / (float)(h << 3);
        __syncthreads();
#pragma unroll
        for (int it = 0; it < (N >> 3) / NT; ++it) {
            const int b = tid + it * NT;
            int j = b & (h - 1);
            int base = ((b >> hb) << (hb + 3)) + j;
            int s0 = swz(base);
            float2 x[8];
#pragma unroll
            for (int k = 0; k < 8; ++k) x[k] = s[s0 ^ swz(k << hb)];
            float2 y[8];
            dft8(x, y, dir);
            if (hb != 0) {
                float ang = astep * (float)j;
                float c, sn;
                __sincosf(ang, &sn, &c);
                float2 w = make_float2(c, sn), wm = w;
                s[s0] = y[0];
#pragma unroll
                for (int m = 1; m < 8; ++m) {
                    s[s0 ^ swz(m << hb)] = cmul(wm, y[m]);
                    wm = cmul(wm, w);
                }
            } else {
#pragma unroll
                for (int m = 0; m < 8; ++m) s[s0 ^ swz(m << hb)] = y[m];
            }
        }
    }
    __syncthreads();
}

// ---------- radix-2 DIF (unswizzled), for the 2048-pt kernel inverse only ----------
template <int LOGN, int NT>
__device__ void fft_dif2(float2* s, int tid, float dir) {
    const int N = 1 << LOGN;
    for (int st = LOGN - 1; st >= 0; --st) {
        __syncthreads();
        int half = 1 << st;
        for (int b = tid; b < (N >> 1); b += NT) {
            int j  = b & (half - 1);
            int i0 = ((b >> st) << (st + 1)) + j;
            int i1 = i0 + half;
            float2 u = s[i0], v = s[i1];
            float2 d = make_float2(u.x - v.x, u.y - v.y);
            s[i0] = make_float2(u.x + v.x, u.y + v.y);
            if (half > 1) {
                float ang = dir * 3.14159265358979f * (float)j / (float)half;
                float c, sn;
                __sincosf(ang, &sn, &c);
                s[i1] = cmul(make_float2(c, sn), d);
            } else {
                s[i1] = d;
            }
        }
    }
    __syncthreads();
}

// ---------- kernel A: k_f[h, f] via Cauchy + Woodbury, collapsed pair algebra ----------
__global__ __launch_bounds__(TPB) void kf_kernel(
    const float* __restrict__ log_dt, const float* __restrict__ w_ri,
    const float* __restrict__ Bri, const float* __restrict__ Cri,
    float2* __restrict__ kf) {
    __shared__ float2 wds[32];
    __shared__ float aab[4][32], rab[4][32];
    __shared__ float qn[32], pn[32];
    const int h   = blockIdx.x;
    const int tid = threadIdx.x;
    const float dt = expf(log_dt[h]);
    if (tid < 32) {
        float wr = w_ri[2 * tid] * dt, wi = w_ri[2 * tid + 1] * dt;
        wds[tid] = make_float2(wr, wi);
        qn[tid]  = wr * wr + wi * wi;
        pn[tid]  = -2.0f * wr;
    }
    __syncthreads();
    if (tid < 128) {
        int a = tid >> 6, b = (tid >> 5) & 1, n = tid & 31;
        const float* Cp = Cri + (((h * 2 + a) * 32) + n) * 2;
        const float* Bp = Bri + (((h * 2 + b) * 32) + n) * 2;
        float Cr = Cp[0], Ci = Cp[1], Br = Bp[0], Bi = Bp[1];
        float2 v = make_float2(Cr * Br + Ci * Bi, Cr * Bi - Ci * Br);  // conj(C)*B
        float2 wd = wds[n];
        aab[a * 2 + b][n] = -2.0f * (v.x * wd.x + v.y * wd.y);
        rab[a * 2 + b][n] = 2.0f * v.x;
    }
    __syncthreads();
    const int by   = blockIdx.y;
    const int fend = (by == 3) ? 2049 : (by + 1) * 512;
    for (int f = by * 512 + tid; f < fend; f += TPB) {
        float th = (6.283185307179586f / 4096.0f) * (float)f;
        float cf = cosf(th), sf = sinf(th);
        float2 den = make_float2(1.0f + cf, -sf);      // 1 + freq
        float zt  = 2.0f * tanf(0.5f * th);
        float zt2 = zt * zt;
        float2 r00 = make_float2(0.f, 0.f), r01 = r00, r10 = r00, r11 = r00;
        for (int n = 0; n < 32; ++n) {
            float c   = qn[n] - zt2;
            float d   = pn[n] * zt;
            float inv = 1.0f / (c * c + d * d);
            float cc = c * inv, dd = d * inv;
            float a0 = aab[0][n], b0 = rab[0][n] * zt;
            r00.x += a0 * cc + b0 * dd; r00.y += b0 * cc - a0 * dd;
            float a1 = aab[1][n], b1 = rab[1][n] * zt;
            r01.x += a1 * cc + b1 * dd; r01.y += b1 * cc - a1 * dd;
            float a2 = aab[2][n], b2 = rab[2][n] * zt;
            r10.x += a2 * cc + b2 * dd; r10.y += b2 * cc - a2 * dd;
            float a3 = aab[3][n], b3 = rab[3][n] * zt;
            r11.x += a3 * cc + b3 * dd; r11.y += b3 * cc - a3 * dd;
        }
        r00.x *= dt; r00.y *= dt; r01.x *= dt; r01.y *= dt;
        r10.x *= dt; r10.y *= dt; r11.x *= dt; r11.y *= dt;
        float2 q  = cdivf(cmul(r01, r10), make_float2(1.0f + r11.x, r11.y));
        float2 k0 = make_float2(r00.x - q.x, r00.y - q.y);
        float2 kv = cmul(k0, cdivf(make_float2(2.0f, 0.0f), den));
        kf[h * 2049 + f] = kv;
    }
}

// ---------- kernel B (fused): irfft -> zero-pad -> rfft8192 -> per-bin LINEAR MAP coeffs ----------
// For each slot p (digit-rev domain): Y'[p] = alpha*Y[p] + beta*conj(Y[pc]) applied in conv.
// alpha = 0.5*(A + s*t2), beta = 0.5*i*c*t2  where (c,s)=e^{-i pi j/4096}, A/t2 from the
// kernel spectrum's Hermitian unpack. Uniform over ALL p incl. DC/Nyquist fold and self-pair.
// Stored fp16: Ct[(h*4096+p)] = {alpha as half2, beta as half2} (8 B).
__global__ __launch_bounds__(KTPB) void kprep_kernel(const float2* __restrict__ kf,
                                                     float2* __restrict__ Ct) {
    __shared__ float2 s[4096];
    const int hh = blockIdx.x, tid = threadIdx.x;
    const float2* X = kf + hh * 2049;
    for (int m = tid; m < 2048; m += KTPB) {
        float2 Xm = X[m];
        float2 Xc = X[2048 - m];
        if (m == 0) { Xm.y = 0.0f; Xc.y = 0.0f; }
        float2 A  = make_float2(Xm.x + Xc.x, Xm.y - Xc.y);
        float2 Bv = make_float2(Xm.x - Xc.x, Xm.y + Xc.y);
        float ang = (3.14159265358979f / 2048.0f) * (float)m;
        float c, sn;
        __sincosf(ang, &sn, &c);
        float2 O = cmul(make_float2(c, sn), Bv);
        s[m] = make_float2(0.5f * (A.x - O.y), 0.5f * (A.y + O.x));
    }
    fft_dif2<11, KTPB>(s, tid, +1.0f);  // inverse, natural-in -> bitrev-out (unswizzled)
    float2 reg[4];
    const float sc = 1.0f / 2048.0f;
#pragma unroll
    for (int i = 0; i < 4; ++i) {
        int t = tid + KTPB * i;  // 0..2047
        float2 v = s[brev11(t)];
        reg[i] = make_float2(v.x * sc, v.y * sc);
    }
    __syncthreads();
#pragma unroll
    for (int i = 0; i < 4; ++i) {
        int t = tid + KTPB * i;
        s[swz(t)]        = reg[i];
        s[swz(t + 2048)] = make_float2(0.f, 0.f);
    }
    fft8_dif<12, KTPB>(s, tid, -1.0f);  // slot p holds Y[rev8(p)]
    float2* C = Ct + (size_t)hh * 4096;
    for (int p = tid; p < 4096; p += KTPB) {
        int j  = rev8(p);
        int jc = (4096 - j) & 4095;
        int pc = rev8(jc);
        float2 Yj = s[swz(p)], Yc = s[swz(pc)];
        float2 A  = make_float2(Yj.x + Yc.x, Yj.y - Yc.y);
        float2 Bv = make_float2(Yj.x - Yc.x, Yj.y + Yc.y);
        float ang = -(3.14159265358979f / 4096.0f) * (float)j;
        float c, sn;
        __sincosf(ang, &sn, &c);
        float2 t2 = cmul(make_float2(c, sn), make_float2(Bv.y, -Bv.x));  // -i*W*Bv
        float2 al = make_float2(0.5f * (A.x + sn * t2.x), 0.5f * (A.y + sn * t2.y));
        float2 be = make_float2(-0.5f * c * t2.y, 0.5f * c * t2.x);      // 0.5*i*c*t2
        __half2 ha = __floats2half2_rn(al.x, al.y);
        __half2 hb = __floats2half2_rn(be.x, be.y);
        float2 raw;
        *(__half2*)&raw.x = ha;
        *(__half2*)&raw.y = hb;
        C[p] = raw;
    }
}

// ---------- transpose in: x[b,t,h] -> xt[(b*512+h), t], float4 both sides ----------
__global__ __launch_bounds__(TPB) void transpose_in(const float* __restrict__ x,
                                                    float* __restrict__ xt) {
    __shared__ float tile[64][65];
    const int b = blockIdx.z, t0 = blockIdx.y * 64, h0 = blockIdx.x * 64;
    const int tid = threadIdx.x;
    const float4* xv = (const float4*)(x + ((size_t)b * 4096 + t0) * 512 + h0);
#pragma unroll
    for (int i = 0; i < 4; ++i) {
        int idx = tid + TPB * i;       // 0..1023
        int tl = idx >> 4, hq = idx & 15;
        float4 v = xv[(size_t)tl * 128 + hq];
        tile[tl][hq * 4 + 0] = v.x; tile[tl][hq * 4 + 1] = v.y;
        tile[tl][hq * 4 + 2] = v.z; tile[tl][hq * 4 + 3] = v.w;
    }
    __syncthreads();
    float* xo = xt + ((size_t)(b * 512 + h0)) * 4096 + t0;
#pragma unroll
    for (int i = 0; i < 4; ++i) {
        int idx = tid + TPB * i;
        int hl = idx >> 4, tq = idx & 15;
        float4 v = make_float4(tile[tq * 4 + 0][hl], tile[tq * 4 + 1][hl],
                               tile[tq * 4 + 2][hl], tile[tq * 4 + 3][hl]);
        ((float4*)(xo + (size_t)hl * 4096))[tq] = v;
    }
}

// ---------- fused conv: y = irfft8192(rfft8192(x)*K~)[0:4096] + D*x, coefficient-map pointwise ----------
__global__ __launch_bounds__(CTPB) void conv_kernel(const float* xt,
                                                    const float2* __restrict__ Ct,
                                                    const float* __restrict__ Dv,
                                                    float* yt) {
    __shared__ float2 s[4096];
    const int row = blockIdx.x, tid = threadIdx.x;
    const int hch = row & 511;
    const int stid = swz(tid);
    const float2* xr = (const float2*)(xt + (size_t)row * 4096);

    // ---- D1 (DIF h=512) in registers; upper half is the zero pad -> dft8z
    {
        float2 x0 = xr[tid], x1 = xr[tid + 512], x2 = xr[tid + 1024], x3 = xr[tid + 1536];
        float2 y[8];
        dft8z(x0, x1, x2, x3, y, -1.0f);
        float ang = -(6.283185307179586f / 4096.0f) * (float)tid;
        float c, sn;
        __sincosf(ang, &sn, &c);
        float2 w = make_float2(c, sn), wm = w;
        s[stid] = y[0];
#pragma unroll
        for (int m = 1; m < 8; ++m) {
            s[stid ^ swz(m << 9)] = cmul(wm, y[m]);
            wm = cmul(wm, w);
        }
    }
    dif_stage<6, -1>(s, tid);
    dif_stage<3, -1>(s, tid);
    dif_stage<0, -1>(s, tid);
    __syncthreads();
    // ---- pointwise: precomputed linear map Y'[p] = a*Y[p] + b*conj(Y[pc])
    const float2* C = Ct + (size_t)hch * 4096;
    const int J0 = rev8(tid);  // p = tid + 512*i -> j = J0 + i
#pragma unroll
    for (int i = 0; i < 8; ++i) {
        int p  = tid + CTPB * i;
        int sp = stid ^ swz(CTPB * i);
        int j  = J0 + i;
        int jc = (4096 - j) & 4095;
        int pc = rev8(jc);
        if (pc < p) continue;  // pair owner has the smaller slot
        float2 Yj = s[sp], Yc = s[swz(pc)];
        float2 raw = C[p];
        float2 al = __half22float2(*(const __half2*)&raw.x);
        float2 be = __half22float2(*(const __half2*)&raw.y);
        s[sp] = cadd(cmul(al, Yj), cmulcj(be, Yc));
        if (pc != p) {
            float2 rawc = C[pc];
            float2 alc = __half22float2(*(const __half2*)&rawc.x);
            float2 bec = __half22float2(*(const __half2*)&rawc.y);
            s[swz(pc)] = cadd(cmul(alc, Yc), cmulcj(bec, Yj));
        }
    }
    dit_stage<0, 1>(s, tid);
    dit_stage<3, 1>(s, tid);
    dit_stage<6, 1>(s, tid);
    __syncthreads();
    // ---- I4 (DIT h=512) in registers; keep only first 4096 samples; fuse D*x skip
    {
        float ang = (6.283185307179586f / 4096.0f) * (float)tid;
        float c, sn;
        __sincosf(ang, &sn, &c);
        float2 w = make_float2(c, sn);
        float2 x[8];
        x[0] = s[stid];
        float2 wm = w;
#pragma unroll
        for (int k = 1; k < 8; ++k) {
            x[k] = cmul(wm, s[stid ^ swz(k << 9)]);
            wm = cmul(wm, w);
        }
        float2 y[4];
        dft8_lo(x, y, 1.0f);
        const float D = Dv[hch];
        float2* yo = (float2*)(yt + (size_t)row * 4096);
        const float sc = 1.0f / 4096.0f;
#pragma unroll
        for (int m = 0; m < 4; ++m) {
            int t2 = tid + (m << 9);
            float2 xin = xr[t2];  // re-read own row (L2-warm); xt/yt alias is per-element safe
            yo[t2] = make_float2(y[m].x * sc + D * xin.x, y[m].y * sc + D * xin.y);
        }
    }
}

// ---------- transpose out (pure): out[b,t,h] = yt[(b*512+h),t] ----------
__global__ __launch_bounds__(TPB) void transpose_out(const float* __restrict__ yt,
                                                     float* __restrict__ out) {
    __shared__ float tile[64][65];
    const int b = blockIdx.z, t0 = blockIdx.y * 64, h0 = blockIdx.x * 64;
    const int tid = threadIdx.x;
    const float* yp = yt + ((size_t)(b * 512 + h0)) * 4096 + t0;
#pragma unroll
    for (int i = 0; i < 4; ++i) {
        int idx = tid + TPB * i;
        int hl = idx >> 4, tq = idx & 15;
        float4 v = ((const float4*)(yp + (size_t)hl * 4096))[tq];
        tile[tq * 4 + 0][hl] = v.x; tile[tq * 4 + 1][hl] = v.y;
        tile[tq * 4 + 2][hl] = v.z; tile[tq * 4 + 3][hl] = v.w;
    }
    __syncthreads();
    float4* ov = (float4*)(out + ((size_t)b * 4096 + t0) * 512 + h0);
#pragma unroll
    for (int i = 0; i < 4; ++i) {
        int idx = tid + TPB * i;
        int tl = idx >> 4, hq = idx & 15;
        float4 v = make_float4(tile[tl][4 * hq + 0], tile[tl][4 * hq + 1],
                               tile[tl][4 * hq + 2], tile[tl][4 * hq + 3]);
        ov[(size_t)tl * 128 + hq] = v;
    }
}

extern "C" void kernel_launch(void* const* d_in, const int* in_sizes, int n_in,
                              void* d_out, int out_size, void* d_ws, size_t ws_size,
                              hipStream_t stream) {
    (void)in_sizes; (void)n_in; (void)out_size; (void)ws_size;
    const float* x      = (const float*)d_in[0];  // [8,4096,512]
    const float* log_dt = (const float*)d_in[1];  // [512]
    const float* w_ri   = (const float*)d_in[2];  // [32,2]
    const float* Bri    = (const float*)d_in[3];  // [512,2,32,2]
    const float* Cri    = (const float*)d_in[4];  // [512,2,32,2]
    const float* Dv     = (const float*)d_in[5];  // [512]
    float* out = (float*)d_out;

    char* ws = (char*)d_ws;
    float*  xt = (float*)(ws);                  // 8*512*4096*4 = 67,108,864 B (reused as yt)
    float2* kf = (float2*)(ws + 67108864);      // 512*2049*8   =  8,392,704 B
    float2* Ct = (float2*)(ws + 75501568);      // 512*4096*8   = 16,777,216 B  (end ~88 MB)

    kf_kernel<<<dim3(512, 4), TPB, 0, stream>>>(log_dt, w_ri, Bri, Cri, kf);
    kprep_kernel<<<512, KTPB, 0, stream>>>(kf, Ct);
    transpose_in<<<dim3(8, 64, 8), TPB, 0, stream>>>(x, xt);
    conv_kernel<<<4096, CTPB, 0, stream>>>(xt, Ct, Dv, xt);  // y(+skip) overwrites xt rows
    transpose_out<<<dim3(8, 64, 8), TPB, 0, stream>>>(xt, out);
}